// Round 6
// baseline (136.202 us; speedup 1.0000x reference)
//
#include <hip/hip_runtime.h>
#include <hip/hip_bf16.h>

#define N_N 128
#define N_C 7
#define N_H 96
#define N_W 192
#define HW (N_H * N_W)            // 18432
#define CHW (N_C * HW)            // 129024
#define NHW (N_N * HW)            // 2359296
#define NPTS 100
#define NK (N_N * N_C)            // 896
#define NK2 (NK / 2)              // 448 float2 per row
#define NK4 (NK / 4)              // 224 float4 per row
#define NV (NHW / 4)              // 589824 float4 per tensor (channel 0)
#define HV (HW / 4)               // 4608
#define CV (CHW / 4)              // 32256
#define SIGMA_F 2.0f

// mono-kernel partitioning
#define GRID_M 1024
#define GB 100                    // gather blocks 0..99
#define BGB (GRID_M - GB)         // 924 bg blocks 100..1023
#define PAIRB 625                 // pair tiles, blocks 0..624
#define TILE 4
#define NTILE (NPTS / TILE)       // 25

// fallback (R5) partitioning
#define BG_BLOCKS 1024
#define PAIR_BLOCKS (NTILE * NTILE)

#define AQ __ATOMIC_ACQUIRE
#define RL __ATOMIC_RELEASE
#define SCOPE __HIP_MEMORY_SCOPE_AGENT

// ===================== single cooperative mono-kernel ======================
__global__ __launch_bounds__(256) void mono_kernel(
        const float* __restrict__ in, const float* __restrict__ tg,
        const int* __restrict__ px, const int* __restrict__ py,
        int* cnts,                          // [48] ints: gather@0, bg@16, pair@32
        double* bgpart,                     // [924]
        double* klpart,                     // [625]
        int* cntpart,                       // [625]
        float* term1,                       // [100]
        unsigned long long* fpr,            // [100]
        float* Pt, float* Gt,               // [100][896]
        float* out) {
    __shared__ __align__(16) float sJ[TILE * NK];   // 14336 B: staged j-rows (also hash scratch)
    __shared__ double sred[256];
    __shared__ int sicnt[256];
    __shared__ float sT1[8];
    __shared__ unsigned long long sFp[8];
    __shared__ int sPx[8], sPy[8];
    __shared__ double skl[4];
    __shared__ int scnt4[4];

    const int b = blockIdx.x;
    const int t = threadIdx.x;
    const int w = t >> 6;
    const int lane = t & 63;
    int* gatherCnt = cnts;
    int* bgCnt = cnts + 16;
    int* pairCnt = cnts + 32;

    if (b < GB) {
        // ---- gather row i + term1 + G fingerprint ----
        const int i = b;
        const int base = py[i] * N_W + px[i];
        float s = 0.0f;
        unsigned long long h = 0ull;
        for (int k = t; k < NK; k += 256) {
            int n = k / N_C, c = k - n * N_C;
            int off = n * CHW + c * HW + base;
            float p = in[off], g = tg[off];
            Pt[i * NK + k] = p;
            Gt[i * NK + k] = g;
            s += (p > 0.0f) ? p * logf(p) : 0.0f;
            unsigned long long m = (unsigned long long)__float_as_uint(g)
                                 ^ (0x9E3779B97F4A7C15ULL * (unsigned long long)(k + 1));
            m *= 0xC2B2AE3D27D4EB4FULL;
            h ^= m ^ (m >> 31);
        }
        float* sf = (float*)sred;
        unsigned long long* sh = (unsigned long long*)sJ;
        sf[t] = s; sh[t] = h;
        __syncthreads();
        for (int off = 128; off > 0; off >>= 1) {
            if (t < off) { sf[t] += sf[t + off]; sh[t] ^= sh[t + off]; }
            __syncthreads();
        }
        if (t == 0) {
            term1[i] = sf[0];
            fpr[i] = sh[0];
            __hip_atomic_fetch_add(gatherCnt, 1, RL, SCOPE);
        }
    } else {
        // ---- bg: BCE-with-logits over channel 0 ----
        const int NT = BGB * 256;
        const float4* in4 = (const float4*)in;
        const float4* tg4 = (const float4*)tg;
        float s = 0.0f;
        for (int e = (b - GB) * 256 + t; e < NV; e += NT) {
            int n = e / HV;
            int r = e - n * HV;
            float4 x4 = in4[n * CV + r];
            float4 t4 = tg4[n * CV + r];
            const float* xp = &x4.x;
            const float* tp = &t4.x;
#pragma unroll
            for (int q = 0; q < 4; ++q) {
                float x = xp[q], tt = tp[q];
                s += fmaxf(x, 0.0f) - x * tt + log1pf(expf(-fabsf(x)));
            }
        }
        float* sf = (float*)sred;
        sf[t] = s;
        __syncthreads();
        for (int off = 128; off > 0; off >>= 1) {
            if (t < off) sf[t] += sf[t + off];
            __syncthreads();
        }
        if (t == 0) {
            bgpart[b - GB] = (double)sf[0];
            __hip_atomic_fetch_add(bgCnt, 1, RL, SCOPE);
        }
    }

    // ---- pairs phase (blocks 0..624), gated on gather completion ----
    if (b < PAIRB) {
        if (t == 0) {
            while (__hip_atomic_load(gatherCnt, AQ, SCOPE) < GB)
                __builtin_amdgcn_s_sleep(2);
        }
        __syncthreads();

        const int ti = b / NTILE;
        const int tj = b - ti * NTILE;
        if (t < 8) {
            int g = (t < 4) ? (ti * TILE + t) : (tj * TILE + (t - 4));
            sT1[t] = term1[g];
            sFp[t] = fpr[g];
            sPx[t] = px[g];
            sPy[t] = py[g];
        }
        {   // stage 4 j-rows of P
            const float4* Pt4 = (const float4*)Pt;
            float4* sJ4 = (float4*)sJ;
            for (int idx = t; idx < TILE * NK4; idx += 256) {
                int r = idx / NK4, q = idx - r * NK4;
                sJ4[idx] = Pt4[(tj * TILE + r) * NK4 + q];
            }
        }
        __syncthreads();

        const int I = ti * TILE + w;
        const float2* PtI = (const float2*)(Pt + I * NK);
        float2 piv[7];
#pragma unroll
        for (int it = 0; it < 7; ++it) piv[it] = PtI[lane + it * 64];

        double kl = 0.0;
        int cnt = 0;
#pragma unroll
        for (int bb = 0; bb < TILE; ++bb) {
            const int J = tj * TILE + bb;
            const float2* pj2 = (const float2*)(sJ + bb * NK);
            float cross = 0.0f;
#pragma unroll
            for (int it = 0; it < 7; ++it) {
                float2 pj = pj2[lane + it * 64];
                cross = fmaf(piv[it].x, pj.x, cross);
                cross = fmaf(piv[it].y, pj.y, cross);
            }
#pragma unroll
            for (int m = 32; m >= 1; m >>= 1) cross += __shfl_xor(cross, m);

            bool eqv;
            if (I == J) {
                eqv = true;                       // masked out anyway
            } else if (sFp[w] != sFp[4 + bb]) {
                eqv = false;                      // fingerprints differ -> rows differ (exact)
            } else {
                // rare: fingerprints match, verify exactly
                const float2* gi = (const float2*)(Gt + I * NK);
                const float2* gj = (const float2*)(Gt + J * NK);
                int ef = 1;
#pragma unroll
                for (int it = 0; it < 7; ++it) {
                    int q = lane + it * 64;
                    float2 a = gi[q], c2 = gj[q];
                    ef &= (a.x == c2.x) & (a.y == c2.y);
                }
                eqv = __all(ef);
            }
            if (lane == 0) {
                float Dij = (sT1[4 + bb] - cross) * (1.0f / (float)N_N);
                float Dji = (sT1[w] - cross) * (1.0f / (float)N_N);
                float L = eqv ? (Dij + Dji)
                              : (float)(N_N * N_C) *
                                (fmaxf(SIGMA_F - Dij, 0.0f) + fmaxf(SIGMA_F - Dji, 0.0f));
                bool mask = (I != J) && (sPx[w] != sPx[4 + bb]) && (sPy[w] != sPy[4 + bb]);
                if (mask) { kl += (double)L; cnt += 1; }
            }
        }
        if (lane == 0) { skl[w] = kl; scnt4[w] = cnt; }
        __syncthreads();
        if (t == 0) {
            klpart[b] = skl[0] + skl[1] + skl[2] + skl[3];
            cntpart[b] = scnt4[0] + scnt4[1] + scnt4[2] + scnt4[3];
            __hip_atomic_fetch_add(pairCnt, 1, RL, SCOPE);
        }
    }

    // ---- finalization by block GRID_M-1 ----
    if (b == GRID_M - 1) {
        if (t == 0) {
            while (__hip_atomic_load(pairCnt, AQ, SCOPE) < PAIRB)
                __builtin_amdgcn_s_sleep(2);
            while (__hip_atomic_load(bgCnt, AQ, SCOPE) < BGB)
                __builtin_amdgcn_s_sleep(2);
        }
        __syncthreads();
        double s = 0.0;
        for (int q = t; q < BGB; q += 256) s += bgpart[q];
        double kq = 0.0;
        int cq = 0;
        for (int q = t; q < PAIRB; q += 256) { kq += klpart[q]; cq += cntpart[q]; }
        sred[t] = s;
        __syncthreads();
        for (int off = 128; off > 0; off >>= 1) {
            if (t < off) sred[t] += sred[t + off];
            __syncthreads();
        }
        double bg_sum = sred[0];
        __syncthreads();
        sred[t] = kq; sicnt[t] = cq;
        __syncthreads();
        for (int off = 128; off > 0; off >>= 1) {
            if (t < off) { sred[t] += sred[t + off]; sicnt[t] += sicnt[t + off]; }
            __syncthreads();
        }
        if (t == 0)
            out[0] = (float)(bg_sum / (double)NHW + sred[0] / (double)sicnt[0]);
    }
}

// ===================== fallback: proven R5 3-kernel path ====================
__global__ __launch_bounds__(256) void fusedA_kernel(
        const float* __restrict__ in, const float* __restrict__ tg,
        const int* __restrict__ px, const int* __restrict__ py,
        double* __restrict__ bgpart, float* __restrict__ Pt,
        float* __restrict__ Gt, float* __restrict__ term1) {
    __shared__ float sdata[256];
    const int b = blockIdx.x;
    const int t = threadIdx.x;
    if (b < BG_BLOCKS) {
        const float4* in4 = (const float4*)in;
        const float4* tg4 = (const float4*)tg;
        float s = 0.0f;
        for (int e = b * 256 + t; e < NV; e += BG_BLOCKS * 256) {
            int n = e / HV;
            int r = e - n * HV;
            float4 x4 = in4[n * CV + r];
            float4 t4 = tg4[n * CV + r];
            const float* xp = &x4.x;
            const float* tp = &t4.x;
#pragma unroll
            for (int q = 0; q < 4; ++q) {
                float x = xp[q], tt = tp[q];
                s += fmaxf(x, 0.0f) - x * tt + log1pf(expf(-fabsf(x)));
            }
        }
        sdata[t] = s;
        __syncthreads();
        for (int off = 128; off > 0; off >>= 1) {
            if (t < off) sdata[t] += sdata[t + off];
            __syncthreads();
        }
        if (t == 0) bgpart[b] = (double)sdata[0];
    } else {
        const int i = b - BG_BLOCKS;
        const int base = py[i] * N_W + px[i];
        float s = 0.0f;
        for (int k = t; k < NK; k += 256) {
            int n = k / N_C;
            int c = k - n * N_C;
            int off = n * CHW + c * HW + base;
            float p = in[off];
            float g = tg[off];
            Pt[i * NK + k] = p;
            Gt[i * NK + k] = g;
            s += (p > 0.0f) ? p * logf(p) : 0.0f;
        }
        sdata[t] = s;
        __syncthreads();
        for (int off = 128; off > 0; off >>= 1) {
            if (t < off) sdata[t] += sdata[t + off];
            __syncthreads();
        }
        if (t == 0) term1[i] = sdata[0];
    }
}

__global__ __launch_bounds__(256) void pairs_kernel(
        const float* __restrict__ Pt, const float* __restrict__ Gt,
        const float* __restrict__ term1,
        const int* __restrict__ px, const int* __restrict__ py,
        double* __restrict__ klpart, int* __restrict__ cntpart) {
    __shared__ float sP[8 * NK];
    __shared__ float sG[8 * NK];
    __shared__ float sT1[8];
    __shared__ int sPx[8], sPy[8];
    __shared__ double skl[4];
    __shared__ int scnt[4];
    const int bt = blockIdx.x;
    const int ti = bt / NTILE;
    const int tj = bt - ti * NTILE;
    const int t = threadIdx.x;
    const int w = t >> 6;
    const int lane = t & 63;
    if (t < 8) {
        int g = (t < 4) ? (ti * TILE + t) : (tj * TILE + (t - 4));
        sT1[t] = term1[g];
        sPx[t] = px[g];
        sPy[t] = py[g];
    }
    {
        const float4* Pt4 = (const float4*)Pt;
        const float4* Gt4 = (const float4*)Gt;
        float4* sP4 = (float4*)sP;
        float4* sG4 = (float4*)sG;
        for (int idx = t; idx < 8 * NK4; idx += 256) {
            int r = idx / NK4;
            int q = idx - r * NK4;
            int g = (r < 4) ? (ti * TILE + r) : (tj * TILE + (r - 4));
            sP4[idx] = Pt4[g * NK4 + q];
            sG4[idx] = Gt4[g * NK4 + q];
        }
    }
    __syncthreads();
    const float2* sP2 = (const float2*)sP;
    const float2* sG2 = (const float2*)sG;
    const int I = ti * TILE + w;
    double kl = 0.0;
    int cnt = 0;
#pragma unroll
    for (int b2 = 0; b2 < TILE; ++b2) {
        const int rj = 4 + b2;
        float cross = 0.0f;
        int eqf = 1;
#pragma unroll
        for (int it = 0; it < 7; ++it) {
            int q = lane + it * 64;
            float2 pi = sP2[w * NK2 + q];
            float2 pj = sP2[rj * NK2 + q];
            float2 gi = sG2[w * NK2 + q];
            float2 gj = sG2[rj * NK2 + q];
            cross = fmaf(pi.x, pj.x, cross);
            cross = fmaf(pi.y, pj.y, cross);
            eqf &= (gi.x == gj.x) & (gi.y == gj.y);
        }
#pragma unroll
        for (int m = 32; m >= 1; m >>= 1) cross += __shfl_xor(cross, m);
        int alleq = __all(eqf);
        if (lane == 0) {
            const int J = tj * TILE + b2;
            float Dij = (sT1[rj] - cross) * (1.0f / (float)N_N);
            float Dji = (sT1[w] - cross) * (1.0f / (float)N_N);
            float L = alleq ? (Dij + Dji)
                            : (float)(N_N * N_C) *
                              (fmaxf(SIGMA_F - Dij, 0.0f) + fmaxf(SIGMA_F - Dji, 0.0f));
            bool mask = (I != J) && (sPx[w] != sPx[rj]) && (sPy[w] != sPy[rj]);
            if (mask) { kl += (double)L; cnt += 1; }
        }
    }
    if (lane == 0) { skl[w] = kl; scnt[w] = cnt; }
    __syncthreads();
    if (t == 0) {
        klpart[bt] = skl[0] + skl[1] + skl[2] + skl[3];
        cntpart[bt] = scnt[0] + scnt[1] + scnt[2] + scnt[3];
    }
}

__global__ __launch_bounds__(256) void final_kernel(
        const double* __restrict__ bgpart, const double* __restrict__ klpart,
        const int* __restrict__ cntpart, float* __restrict__ out) {
    __shared__ double sdata[256];
    __shared__ int scnt[256];
    const int t = threadIdx.x;
    double s = 0.0;
    for (int q = t; q < BG_BLOCKS; q += 256) s += bgpart[q];
    double kl = 0.0;
    int cnt = 0;
    for (int q = t; q < PAIR_BLOCKS; q += 256) { kl += klpart[q]; cnt += cntpart[q]; }
    sdata[t] = s;
    __syncthreads();
    for (int off = 128; off > 0; off >>= 1) {
        if (t < off) sdata[t] += sdata[t + off];
        __syncthreads();
    }
    double bg_sum = sdata[0];
    __syncthreads();
    sdata[t] = kl;
    scnt[t] = cnt;
    __syncthreads();
    for (int off = 128; off > 0; off >>= 1) {
        if (t < off) { sdata[t] += sdata[t + off]; scnt[t] += scnt[t + off]; }
        __syncthreads();
    }
    if (t == 0)
        out[0] = (float)(bg_sum / (double)NHW + sdata[0] / (double)scnt[0]);
}

// ---------------- launch ---------------------------------------------------
extern "C" void kernel_launch(void* const* d_in, const int* in_sizes, int n_in,
                              void* d_out, int out_size, void* d_ws, size_t ws_size,
                              hipStream_t stream) {
    const float* inputs  = (const float*)d_in[0];
    const float* targets = (const float*)d_in[1];
    const int*   px      = (const int*)d_in[2];
    const int*   py      = (const int*)d_in[3];
    float* out = (float*)d_out;

    char* ws = (char*)d_ws;
    int*    cnts    = (int*)ws;                          // 192 B
    double* bgpart  = (double*)(ws + 256);               // 1024*8 max
    double* klpart  = (double*)(ws + 8448);              // 625*8
    int*    cntpart = (int*)(ws + 13456);                // 625*4
    float*  term1   = (float*)(ws + 16000);              // 100*4
    unsigned long long* fpr = (unsigned long long*)(ws + 16448);  // 100*8
    float*  Pt      = (float*)(ws + 17280);              // 358400
    float*  Gt      = (float*)(ws + 375680);             // 358400

    hipError_t err = hipMemsetAsync(cnts, 0, 192, stream);
    if (err == hipSuccess) {
        const float* a0 = inputs; const float* a1 = targets;
        const int* a2 = px; const int* a3 = py;
        int* a4 = cnts; double* a5 = bgpart; double* a6 = klpart;
        int* a7 = cntpart; float* a8 = term1; unsigned long long* a9 = fpr;
        float* a10 = Pt; float* a11 = Gt; float* a12 = out;
        void* args[13] = {&a0, &a1, &a2, &a3, &a4, &a5, &a6,
                          &a7, &a8, &a9, &a10, &a11, &a12};
        err = hipLaunchCooperativeKernel((void*)mono_kernel, dim3(GRID_M),
                                         dim3(256), args, 0, stream);
    }
    if (err != hipSuccess) {
        // fallback: proven 3-kernel path
        fusedA_kernel<<<BG_BLOCKS + NPTS, 256, 0, stream>>>(
            inputs, targets, px, py, bgpart, Pt, Gt, term1);
        pairs_kernel<<<PAIR_BLOCKS, 256, 0, stream>>>(
            Pt, Gt, term1, px, py, klpart, cntpart);
        final_kernel<<<1, 256, 0, stream>>>(bgpart, klpart, cntpart, out);
    }
}

// Round 7
// 111.828 us; speedup vs baseline: 1.2180x; 1.2180x over previous
//
#include <hip/hip_runtime.h>
#include <hip/hip_bf16.h>

#define N_N 128
#define N_C 7
#define N_H 96
#define N_W 192
#define HW (N_H * N_W)            // 18432
#define CHW (N_C * HW)            // 129024
#define NHW (N_N * HW)            // 2359296
#define NPTS 100
#define NK (N_N * N_C)            // 896
#define NK2 (NK / 2)              // 448 float2 per row
#define NK4 (NK / 4)              // 224 float4 per row
#define NV (NHW / 4)              // 589824 float4 per tensor (channel 0)
#define HV (HW / 4)               // 4608
#define CV (CHW / 4)              // 32256
#define SIGMA_F 2.0f

// mono-kernel partitioning: pairs and bg are DISJOINT so they overlap
#define GRID_M 1024
#define GB 100                    // gather blocks 0..99 (subset of pair blocks)
#define PAIRB 625                 // pair tiles, blocks 0..624
#define BGB (GRID_M - PAIRB)      // 399 bg blocks, 625..1023
#define TILE 4
#define NTILE (NPTS / TILE)       // 25

// fallback (R5) partitioning
#define BG_BLOCKS 1024
#define PAIR_BLOCKS (NTILE * NTILE)

#define AQ __ATOMIC_ACQUIRE
#define RL __ATOMIC_RELEASE
#define RX __ATOMIC_RELAXED
#define SCOPE __HIP_MEMORY_SCOPE_AGENT

// ===================== single cooperative mono-kernel ======================
__global__ __launch_bounds__(256) void mono_kernel(
        const float* __restrict__ in, const float* __restrict__ tg,
        const int* __restrict__ px, const int* __restrict__ py,
        int* cnts,                          // gatherCnt@0, allCnt@16 (ints)
        double* bgpart,                     // [399]
        double* klpart,                     // [625]
        int* cntpart,                       // [625]
        float* term1,                       // [100]
        unsigned long long* fpr,            // [100]
        float* Pt, float* Gt,               // [100][896]
        float* out) {
    __shared__ __align__(16) float sJ[TILE * NK];   // staged j-rows / hash scratch
    __shared__ double sred[256];
    __shared__ int sicnt[256];
    __shared__ float sT1[8];
    __shared__ unsigned long long sFp[8];
    __shared__ int sPx[8], sPy[8];
    __shared__ double skl[4];
    __shared__ int scnt4[4];
    __shared__ int slast;

    const int b = blockIdx.x;
    const int t = threadIdx.x;
    const int w = t >> 6;
    const int lane = t & 63;
    int* gatherCnt = cnts;
    int* allCnt = cnts + 16;
    int oldAll = -1;

    if (b < GB) {
        // ---- gather row b (transposed) + term1 + G fingerprint ----
        const int i = b;
        const int base = py[i] * N_W + px[i];
        float s = 0.0f;
        unsigned long long h = 0ull;
        for (int k = t; k < NK; k += 256) {
            int n = k / N_C, c = k - n * N_C;
            int off = n * CHW + c * HW + base;
            float p = in[off], g = tg[off];
            Pt[i * NK + k] = p;
            Gt[i * NK + k] = g;
            s += (p > 0.0f) ? p * logf(p) : 0.0f;
            unsigned long long m = (unsigned long long)__float_as_uint(g)
                                 ^ (0x9E3779B97F4A7C15ULL * (unsigned long long)(k + 1));
            m *= 0xC2B2AE3D27D4EB4FULL;
            h ^= m ^ (m >> 31);
        }
        float* sf = (float*)sred;
        unsigned long long* sh = (unsigned long long*)sJ;
        sf[t] = s; sh[t] = h;
        __syncthreads();
        for (int off = 128; off > 0; off >>= 1) {
            if (t < off) { sf[t] += sf[t + off]; sh[t] ^= sh[t + off]; }
            __syncthreads();
        }
        if (t == 0) {
            term1[i] = sf[0];
            fpr[i] = sh[0];
            __hip_atomic_fetch_add(gatherCnt, 1, RL, SCOPE);  // ONE release per block
        }
        __syncthreads();
    }

    if (b < PAIRB) {
        // ---- pair tile: gate on gather with RELAXED polls, ONE acquire ----
        if (t == 0) {
            while (__hip_atomic_load(gatherCnt, RX, SCOPE) < GB)
                __builtin_amdgcn_s_sleep(2);
        }
        __syncthreads();
        __builtin_amdgcn_fence(__ATOMIC_ACQUIRE, "agent");    // ONE invalidate

        const int ti = b / NTILE;
        const int tj = b - ti * NTILE;
        if (t < 8) {
            int g = (t < 4) ? (ti * TILE + t) : (tj * TILE + (t - 4));
            sT1[t] = term1[g];
            sFp[t] = fpr[g];
            sPx[t] = px[g];
            sPy[t] = py[g];
        }
        {   // stage 4 j-rows of P in LDS
            const float4* Pt4 = (const float4*)Pt;
            float4* sJ4 = (float4*)sJ;
            for (int idx = t; idx < TILE * NK4; idx += 256) {
                int r = idx / NK4, q = idx - r * NK4;
                sJ4[idx] = Pt4[(tj * TILE + r) * NK4 + q];
            }
        }
        __syncthreads();

        const int I = ti * TILE + w;
        const float2* PtI = (const float2*)(Pt + I * NK);
        float2 piv[7];
#pragma unroll
        for (int it = 0; it < 7; ++it) piv[it] = PtI[lane + it * 64];

        double kl = 0.0;
        int cnt = 0;
#pragma unroll
        for (int bb = 0; bb < TILE; ++bb) {
            const int J = tj * TILE + bb;
            const float2* pj2 = (const float2*)(sJ + bb * NK);
            float cross = 0.0f;
#pragma unroll
            for (int it = 0; it < 7; ++it) {
                float2 pj = pj2[lane + it * 64];
                cross = fmaf(piv[it].x, pj.x, cross);
                cross = fmaf(piv[it].y, pj.y, cross);
            }
#pragma unroll
            for (int m = 32; m >= 1; m >>= 1) cross += __shfl_xor(cross, m);

            bool eqv;
            if (I == J) {
                eqv = true;                       // masked out anyway
            } else if (sFp[w] != sFp[4 + bb]) {
                eqv = false;                      // distinct fingerprint -> rows differ
            } else {
                // fingerprints match: verify exactly (rare)
                const float2* gi = (const float2*)(Gt + I * NK);
                const float2* gj = (const float2*)(Gt + J * NK);
                int ef = 1;
#pragma unroll
                for (int it = 0; it < 7; ++it) {
                    int q = lane + it * 64;
                    float2 a = gi[q], c2 = gj[q];
                    ef &= (a.x == c2.x) & (a.y == c2.y);
                }
                eqv = __all(ef);
            }
            if (lane == 0) {
                float Dij = (sT1[4 + bb] - cross) * (1.0f / (float)N_N);
                float Dji = (sT1[w] - cross) * (1.0f / (float)N_N);
                float L = eqv ? (Dij + Dji)
                              : (float)(N_N * N_C) *
                                (fmaxf(SIGMA_F - Dij, 0.0f) + fmaxf(SIGMA_F - Dji, 0.0f));
                bool mask = (I != J) && (sPx[w] != sPx[4 + bb]) && (sPy[w] != sPy[4 + bb]);
                if (mask) { kl += (double)L; cnt += 1; }
            }
        }
        if (lane == 0) { skl[w] = kl; scnt4[w] = cnt; }
        __syncthreads();
        if (t == 0) {
            klpart[b] = skl[0] + skl[1] + skl[2] + skl[3];
            cntpart[b] = scnt4[0] + scnt4[1] + scnt4[2] + scnt4[3];
            oldAll = __hip_atomic_fetch_add(allCnt, 1, RL, SCOPE);  // ONE release
        }
    } else {
        // ---- bg: BCE-with-logits over channel 0, 399 blocks ----
        const int NT = BGB * 256;
        const float4* in4 = (const float4*)in;
        const float4* tg4 = (const float4*)tg;
        float s = 0.0f;
        for (int e = (b - PAIRB) * 256 + t; e < NV; e += NT) {
            int n = e / HV;
            int r = e - n * HV;
            float4 x4 = in4[n * CV + r];
            float4 t4 = tg4[n * CV + r];
            const float* xp = &x4.x;
            const float* tp = &t4.x;
#pragma unroll
            for (int q = 0; q < 4; ++q) {
                float x = xp[q], tt = tp[q];
                s += fmaxf(x, 0.0f) - x * tt + log1pf(expf(-fabsf(x)));
            }
        }
        float* sf = (float*)sred;
        sf[t] = s;
        __syncthreads();
        for (int off = 128; off > 0; off >>= 1) {
            if (t < off) sf[t] += sf[t + off];
            __syncthreads();
        }
        if (t == 0) {
            bgpart[b - PAIRB] = (double)sf[0];
            oldAll = __hip_atomic_fetch_add(allCnt, 1, RL, SCOPE);  // ONE release
        }
    }

    // ---- finalization: the block whose increment completed the grid ----
    if (t == 0) slast = (oldAll == GRID_M - 1) ? 1 : 0;
    __syncthreads();
    if (slast) {
        __builtin_amdgcn_fence(__ATOMIC_ACQUIRE, "agent");    // ONE invalidate
        double s = 0.0;
        for (int q = t; q < BGB; q += 256) s += bgpart[q];
        double kq = 0.0;
        int cq = 0;
        for (int q = t; q < PAIRB; q += 256) { kq += klpart[q]; cq += cntpart[q]; }
        sred[t] = s;
        __syncthreads();
        for (int off = 128; off > 0; off >>= 1) {
            if (t < off) sred[t] += sred[t + off];
            __syncthreads();
        }
        double bg_sum = sred[0];
        __syncthreads();
        sred[t] = kq; sicnt[t] = cq;
        __syncthreads();
        for (int off = 128; off > 0; off >>= 1) {
            if (t < off) { sred[t] += sred[t + off]; sicnt[t] += sicnt[t + off]; }
            __syncthreads();
        }
        if (t == 0)
            out[0] = (float)(bg_sum / (double)NHW + sred[0] / (double)sicnt[0]);
    }
}

// ===================== fallback: proven R5 3-kernel path ====================
__global__ __launch_bounds__(256) void fusedA_kernel(
        const float* __restrict__ in, const float* __restrict__ tg,
        const int* __restrict__ px, const int* __restrict__ py,
        double* __restrict__ bgpart, float* __restrict__ Pt,
        float* __restrict__ Gt, float* __restrict__ term1) {
    __shared__ float sdata[256];
    const int b = blockIdx.x;
    const int t = threadIdx.x;
    if (b < BG_BLOCKS) {
        const float4* in4 = (const float4*)in;
        const float4* tg4 = (const float4*)tg;
        float s = 0.0f;
        for (int e = b * 256 + t; e < NV; e += BG_BLOCKS * 256) {
            int n = e / HV;
            int r = e - n * HV;
            float4 x4 = in4[n * CV + r];
            float4 t4 = tg4[n * CV + r];
            const float* xp = &x4.x;
            const float* tp = &t4.x;
#pragma unroll
            for (int q = 0; q < 4; ++q) {
                float x = xp[q], tt = tp[q];
                s += fmaxf(x, 0.0f) - x * tt + log1pf(expf(-fabsf(x)));
            }
        }
        sdata[t] = s;
        __syncthreads();
        for (int off = 128; off > 0; off >>= 1) {
            if (t < off) sdata[t] += sdata[t + off];
            __syncthreads();
        }
        if (t == 0) bgpart[b] = (double)sdata[0];
    } else {
        const int i = b - BG_BLOCKS;
        const int base = py[i] * N_W + px[i];
        float s = 0.0f;
        for (int k = t; k < NK; k += 256) {
            int n = k / N_C;
            int c = k - n * N_C;
            int off = n * CHW + c * HW + base;
            float p = in[off];
            float g = tg[off];
            Pt[i * NK + k] = p;
            Gt[i * NK + k] = g;
            s += (p > 0.0f) ? p * logf(p) : 0.0f;
        }
        sdata[t] = s;
        __syncthreads();
        for (int off = 128; off > 0; off >>= 1) {
            if (t < off) sdata[t] += sdata[t + off];
            __syncthreads();
        }
        if (t == 0) term1[i] = sdata[0];
    }
}

__global__ __launch_bounds__(256) void pairs_kernel(
        const float* __restrict__ Pt, const float* __restrict__ Gt,
        const float* __restrict__ term1,
        const int* __restrict__ px, const int* __restrict__ py,
        double* __restrict__ klpart, int* __restrict__ cntpart) {
    __shared__ float sP[8 * NK];
    __shared__ float sG[8 * NK];
    __shared__ float sT1[8];
    __shared__ int sPx[8], sPy[8];
    __shared__ double skl[4];
    __shared__ int scnt[4];
    const int bt = blockIdx.x;
    const int ti = bt / NTILE;
    const int tj = bt - ti * NTILE;
    const int t = threadIdx.x;
    const int w = t >> 6;
    const int lane = t & 63;
    if (t < 8) {
        int g = (t < 4) ? (ti * TILE + t) : (tj * TILE + (t - 4));
        sT1[t] = term1[g];
        sPx[t] = px[g];
        sPy[t] = py[g];
    }
    {
        const float4* Pt4 = (const float4*)Pt;
        const float4* Gt4 = (const float4*)Gt;
        float4* sP4 = (float4*)sP;
        float4* sG4 = (float4*)sG;
        for (int idx = t; idx < 8 * NK4; idx += 256) {
            int r = idx / NK4;
            int q = idx - r * NK4;
            int g = (r < 4) ? (ti * TILE + r) : (tj * TILE + (r - 4));
            sP4[idx] = Pt4[g * NK4 + q];
            sG4[idx] = Gt4[g * NK4 + q];
        }
    }
    __syncthreads();
    const float2* sP2 = (const float2*)sP;
    const float2* sG2 = (const float2*)sG;
    const int I = ti * TILE + w;
    double kl = 0.0;
    int cnt = 0;
#pragma unroll
    for (int b2 = 0; b2 < TILE; ++b2) {
        const int rj = 4 + b2;
        float cross = 0.0f;
        int eqf = 1;
#pragma unroll
        for (int it = 0; it < 7; ++it) {
            int q = lane + it * 64;
            float2 pi = sP2[w * NK2 + q];
            float2 pj = sP2[rj * NK2 + q];
            float2 gi = sG2[w * NK2 + q];
            float2 gj = sG2[rj * NK2 + q];
            cross = fmaf(pi.x, pj.x, cross);
            cross = fmaf(pi.y, pj.y, cross);
            eqf &= (gi.x == gj.x) & (gi.y == gj.y);
        }
#pragma unroll
        for (int m = 32; m >= 1; m >>= 1) cross += __shfl_xor(cross, m);
        int alleq = __all(eqf);
        if (lane == 0) {
            const int J = tj * TILE + b2;
            float Dij = (sT1[rj] - cross) * (1.0f / (float)N_N);
            float Dji = (sT1[w] - cross) * (1.0f / (float)N_N);
            float L = alleq ? (Dij + Dji)
                            : (float)(N_N * N_C) *
                              (fmaxf(SIGMA_F - Dij, 0.0f) + fmaxf(SIGMA_F - Dji, 0.0f));
            bool mask = (I != J) && (sPx[w] != sPx[rj]) && (sPy[w] != sPy[rj]);
            if (mask) { kl += (double)L; cnt += 1; }
        }
    }
    if (lane == 0) { skl[w] = kl; scnt[w] = cnt; }
    __syncthreads();
    if (t == 0) {
        klpart[bt] = skl[0] + skl[1] + skl[2] + skl[3];
        cntpart[bt] = scnt[0] + scnt[1] + scnt[2] + scnt[3];
    }
}

__global__ __launch_bounds__(256) void final_kernel(
        const double* __restrict__ bgpart, const double* __restrict__ klpart,
        const int* __restrict__ cntpart, float* __restrict__ out) {
    __shared__ double sdata[256];
    __shared__ int scnt[256];
    const int t = threadIdx.x;
    double s = 0.0;
    for (int q = t; q < BG_BLOCKS; q += 256) s += bgpart[q];
    double kl = 0.0;
    int cnt = 0;
    for (int q = t; q < PAIR_BLOCKS; q += 256) { kl += klpart[q]; cnt += cntpart[q]; }
    sdata[t] = s;
    __syncthreads();
    for (int off = 128; off > 0; off >>= 1) {
        if (t < off) sdata[t] += sdata[t + off];
        __syncthreads();
    }
    double bg_sum = sdata[0];
    __syncthreads();
    sdata[t] = kl;
    scnt[t] = cnt;
    __syncthreads();
    for (int off = 128; off > 0; off >>= 1) {
        if (t < off) { sdata[t] += sdata[t + off]; scnt[t] += scnt[t + off]; }
        __syncthreads();
    }
    if (t == 0)
        out[0] = (float)(bg_sum / (double)NHW + sdata[0] / (double)scnt[0]);
}

// ---------------- launch ---------------------------------------------------
extern "C" void kernel_launch(void* const* d_in, const int* in_sizes, int n_in,
                              void* d_out, int out_size, void* d_ws, size_t ws_size,
                              hipStream_t stream) {
    const float* inputs  = (const float*)d_in[0];
    const float* targets = (const float*)d_in[1];
    const int*   px      = (const int*)d_in[2];
    const int*   py      = (const int*)d_in[3];
    float* out = (float*)d_out;

    char* ws = (char*)d_ws;
    int*    cnts    = (int*)ws;                          // 128 B used
    double* bgpart  = (double*)(ws + 256);               // up to 1024*8
    double* klpart  = (double*)(ws + 8448);              // 625*8
    int*    cntpart = (int*)(ws + 13456);                // 625*4
    float*  term1   = (float*)(ws + 16000);              // 100*4
    unsigned long long* fpr = (unsigned long long*)(ws + 16448);  // 100*8
    float*  Pt      = (float*)(ws + 17280);              // 358400
    float*  Gt      = (float*)(ws + 375680);             // 358400

    hipError_t err = hipMemsetAsync(cnts, 0, 128, stream);
    if (err == hipSuccess) {
        const float* a0 = inputs; const float* a1 = targets;
        const int* a2 = px; const int* a3 = py;
        int* a4 = cnts; double* a5 = bgpart; double* a6 = klpart;
        int* a7 = cntpart; float* a8 = term1; unsigned long long* a9 = fpr;
        float* a10 = Pt; float* a11 = Gt; float* a12 = out;
        void* args[13] = {&a0, &a1, &a2, &a3, &a4, &a5, &a6,
                          &a7, &a8, &a9, &a10, &a11, &a12};
        err = hipLaunchCooperativeKernel((void*)mono_kernel, dim3(GRID_M),
                                         dim3(256), args, 0, stream);
    }
    if (err != hipSuccess) {
        // fallback: proven 3-kernel path
        fusedA_kernel<<<BG_BLOCKS + NPTS, 256, 0, stream>>>(
            inputs, targets, px, py, bgpart, Pt, Gt, term1);
        pairs_kernel<<<PAIR_BLOCKS, 256, 0, stream>>>(
            Pt, Gt, term1, px, py, klpart, cntpart);
        final_kernel<<<1, 256, 0, stream>>>(bgpart, klpart, cntpart, out);
    }
}

// Round 8
// 37.092 us; speedup vs baseline: 3.6720x; 3.0149x over previous
//
#include <hip/hip_runtime.h>
#include <hip/hip_bf16.h>

#define N_N 128
#define N_C 7
#define N_H 96
#define N_W 192
#define HW (N_H * N_W)            // 18432
#define CHW (N_C * HW)            // 129024
#define NHW (N_N * HW)            // 2359296
#define NPTS 100
#define NK (N_N * N_C)            // 896
#define NK2 (NK / 2)              // 448 float2 per row
#define NK4 (NK / 4)              // 224 float4 per row
#define NV (NHW / 4)              // 589824 float4 per tensor (channel 0)
#define HV (HW / 4)               // 4608
#define CV (CHW / 4)              // 32256
#define SIGMA_F 2.0f

#define BG_BLOCKS 1024
#define TILE 4
#define NTILE (NPTS / TILE)       // 25
#define PAIRT (NTILE * (NTILE + 1) / 2)   // 325 tiles with ti<=tj

#define RL __ATOMIC_RELEASE
#define SCOPE __HIP_MEMORY_SCOPE_AGENT

// ---------------- kernel 1: bg partials + gather/transpose/term1/fingerprint
// blocks 0..1023   : BCE-with-logits partial sums over channel 0
// blocks 1024..1123: gather row i (transposed) + term1[i] + G fingerprint
__global__ __launch_bounds__(256) void fusedA_kernel(
        const float* __restrict__ in, const float* __restrict__ tg,
        const int* __restrict__ px, const int* __restrict__ py,
        double* __restrict__ bgpart,        // [1024]
        float* __restrict__ Pt,             // [100][896]
        float* __restrict__ Gt,             // [100][896]
        float* __restrict__ term1,          // [100]
        unsigned long long* __restrict__ fpr) {  // [100]
    __shared__ float sdata[256];
    __shared__ unsigned long long sh[256];
    const int b = blockIdx.x;
    const int t = threadIdx.x;

    if (b < BG_BLOCKS) {
        const float4* in4 = (const float4*)in;
        const float4* tg4 = (const float4*)tg;
        float s = 0.0f;
        for (int e = b * 256 + t; e < NV; e += BG_BLOCKS * 256) {
            int n = e / HV;
            int r = e - n * HV;
            float4 x4 = in4[n * CV + r];
            float4 t4 = tg4[n * CV + r];
            const float* xp = &x4.x;
            const float* tp = &t4.x;
#pragma unroll
            for (int q = 0; q < 4; ++q) {
                float x = xp[q], tt = tp[q];
                s += fmaxf(x, 0.0f) - x * tt + log1pf(expf(-fabsf(x)));
            }
        }
        sdata[t] = s;
        __syncthreads();
        for (int off = 128; off > 0; off >>= 1) {
            if (t < off) sdata[t] += sdata[t + off];
            __syncthreads();
        }
        if (t == 0) bgpart[b] = (double)sdata[0];
    } else {
        const int i = b - BG_BLOCKS;          // 0..99
        const int base = py[i] * N_W + px[i];
        float s = 0.0f;
        unsigned long long h = 0ull;
        for (int k = t; k < NK; k += 256) {
            int n = k / N_C;
            int c = k - n * N_C;
            int off = n * CHW + c * HW + base;
            float p = in[off];
            float g = tg[off];
            Pt[i * NK + k] = p;
            Gt[i * NK + k] = g;
            s += (p > 0.0f) ? p * logf(p) : 0.0f;
            unsigned long long m = (unsigned long long)__float_as_uint(g)
                                 ^ (0x9E3779B97F4A7C15ULL * (unsigned long long)(k + 1));
            m *= 0xC2B2AE3D27D4EB4FULL;
            h ^= m ^ (m >> 31);
        }
        sdata[t] = s;
        sh[t] = h;
        __syncthreads();
        for (int off = 128; off > 0; off >>= 1) {
            if (t < off) { sdata[t] += sdata[t + off]; sh[t] ^= sh[t + off]; }
            __syncthreads();
        }
        if (t == 0) { term1[i] = sdata[0]; fpr[i] = sh[0]; }
    }
}

// ---------------- kernel 2: upper-triangle LDS-tiled pairs + finalization ---
// 325 blocks: tile (ti,tj), ti<=tj. Wave w owns local i-row w; 4 local j's.
// P-only staging (fingerprints replace G). Last-done block finalizes.
__global__ __launch_bounds__(256) void pairsfin_kernel(
        const float* __restrict__ Pt, const float* __restrict__ Gt,
        const float* __restrict__ term1,
        const int* __restrict__ px, const int* __restrict__ py,
        const unsigned long long* __restrict__ fpr,
        const double* __restrict__ bgpart,   // [1024]
        double* __restrict__ klpart,         // [325]
        int* __restrict__ cntpart,           // [325]
        int* __restrict__ doneCnt,           // [1], zeroed per launch
        float* __restrict__ out) {
    __shared__ __align__(16) float sPI[TILE * NK];   // 14336 B
    __shared__ __align__(16) float sPJ[TILE * NK];   // 14336 B
    __shared__ float sT1[8];
    __shared__ unsigned long long sFp[8];
    __shared__ int sPx[8], sPy[8];
    __shared__ double skl[4];
    __shared__ int scnt4[4];
    __shared__ int slast;
    __shared__ double sred[256];
    __shared__ int sicnt[256];

    const int bidx = blockIdx.x;
    const int t = threadIdx.x;
    const int w = t >> 6;
    const int lane = t & 63;

    // decode bidx -> (ti, tj) with ti <= tj
    int ti = 0, rem = bidx;
    while (rem >= NTILE - ti) { rem -= NTILE - ti; ++ti; }
    const int tj = ti + rem;

    if (t < 8) {
        int g = (t < 4) ? (ti * TILE + t) : (tj * TILE + (t - 4));
        sT1[t] = term1[g];
        sFp[t] = fpr[g];
        sPx[t] = px[g];
        sPy[t] = py[g];
    }
    {   // stage 4 i-rows and 4 j-rows of P (float4 coalesced, 7/thread)
        const float4* Pt4 = (const float4*)Pt;
        float4* sI4 = (float4*)sPI;
        float4* sJ4 = (float4*)sPJ;
        for (int idx = t; idx < TILE * NK4; idx += 256) {
            int r = idx / NK4, q = idx - r * NK4;
            sI4[idx] = Pt4[(ti * TILE + r) * NK4 + q];
            sJ4[idx] = Pt4[(tj * TILE + r) * NK4 + q];
        }
    }
    __syncthreads();

    const float2* sPI2 = (const float2*)sPI;
    const int I = ti * TILE + w;
    float2 piv[7];
#pragma unroll
    for (int it = 0; it < 7; ++it) piv[it] = sPI2[w * NK2 + lane + it * 64];

    double kl = 0.0;
    int cnt = 0;
#pragma unroll
    for (int bb = 0; bb < TILE; ++bb) {
        const int J = tj * TILE + bb;
        const float2* pj2 = (const float2*)(sPJ + bb * NK);
        float cross = 0.0f;
#pragma unroll
        for (int it = 0; it < 7; ++it) {
            float2 pj = pj2[lane + it * 64];
            cross = fmaf(piv[it].x, pj.x, cross);
            cross = fmaf(piv[it].y, pj.y, cross);
        }
#pragma unroll
        for (int m = 32; m >= 1; m >>= 1) cross += __shfl_xor(cross, m);

        bool eqv;
        if (I == J) {
            eqv = true;                          // masked out anyway
        } else if (sFp[w] != sFp[4 + bb]) {
            eqv = false;                         // fp differ -> rows differ (exact)
        } else {
            // rare: fingerprints match, verify exactly from global Gt
            const float2* gi = (const float2*)(Gt + I * NK);
            const float2* gj = (const float2*)(Gt + J * NK);
            int ef = 1;
#pragma unroll
            for (int it = 0; it < 7; ++it) {
                int q = lane + it * 64;
                float2 a = gi[q], c2 = gj[q];
                ef &= (a.x == c2.x) & (a.y == c2.y);
            }
            eqv = __all(ef);
        }
        if (lane == 0) {
            float Dij = (sT1[4 + bb] - cross) * (1.0f / (float)N_N);
            float Dji = (sT1[w] - cross) * (1.0f / (float)N_N);
            float L = eqv ? (Dij + Dji)
                          : (float)(N_N * N_C) *
                            (fmaxf(SIGMA_F - Dij, 0.0f) + fmaxf(SIGMA_F - Dji, 0.0f));
            // count each unordered pair once: need I<J (diagonal tiles have I>J cases)
            bool mask = (I < J) && (sPx[w] != sPx[4 + bb]) && (sPy[w] != sPy[4 + bb]);
            if (mask) { kl += (double)L; cnt += 1; }
        }
    }

    if (lane == 0) { skl[w] = kl; scnt4[w] = cnt; }
    __syncthreads();
    if (t == 0) {
        klpart[bidx] = skl[0] + skl[1] + skl[2] + skl[3];
        cntpart[bidx] = scnt4[0] + scnt4[1] + scnt4[2] + scnt4[3];
        // release: prior stores visible to whoever observes the increment
        int old = __hip_atomic_fetch_add(doneCnt, 1, RL, SCOPE);
        slast = (old == PAIRT - 1) ? 1 : 0;
    }
    __syncthreads();

    if (slast) {
        __builtin_amdgcn_fence(__ATOMIC_ACQUIRE, "agent");   // one invalidate
        double s = 0.0;
        for (int q = t; q < BG_BLOCKS; q += 256) s += bgpart[q];
        double kq = 0.0;
        int cq = 0;
        for (int q = t; q < PAIRT; q += 256) { kq += klpart[q]; cq += cntpart[q]; }
        sred[t] = s;
        __syncthreads();
        for (int off = 128; off > 0; off >>= 1) {
            if (t < off) sred[t] += sred[t + off];
            __syncthreads();
        }
        double bg_sum = sred[0];
        __syncthreads();
        sred[t] = kq;
        sicnt[t] = cq;
        __syncthreads();
        for (int off = 128; off > 0; off >>= 1) {
            if (t < off) { sred[t] += sred[t + off]; sicnt[t] += sicnt[t + off]; }
            __syncthreads();
        }
        if (t == 0)
            out[0] = (float)(bg_sum / (double)NHW + sred[0] / (double)sicnt[0]);
    }
}

// ---------------- launch ---------------------------------------------------
extern "C" void kernel_launch(void* const* d_in, const int* in_sizes, int n_in,
                              void* d_out, int out_size, void* d_ws, size_t ws_size,
                              hipStream_t stream) {
    const float* inputs  = (const float*)d_in[0];
    const float* targets = (const float*)d_in[1];
    const int*   px      = (const int*)d_in[2];
    const int*   py      = (const int*)d_in[3];
    float* out = (float*)d_out;

    char* ws = (char*)d_ws;
    int*    doneCnt = (int*)ws;                           // 128 B reserved
    double* bgpart  = (double*)(ws + 256);                // 1024*8 = 8192
    double* klpart  = (double*)(ws + 8448);               // 325*8 = 2600
    int*    cntpart = (int*)(ws + 11264);                 // 325*4 = 1300
    float*  term1   = (float*)(ws + 12800);               // 100*4
    unsigned long long* fpr = (unsigned long long*)(ws + 13312);  // 100*8
    float*  Pt      = (float*)(ws + 14336);               // 358400
    float*  Gt      = (float*)(ws + 372736);              // 358400

    hipMemsetAsync(doneCnt, 0, 128, stream);
    fusedA_kernel<<<BG_BLOCKS + NPTS, 256, 0, stream>>>(
        inputs, targets, px, py, bgpart, Pt, Gt, term1, fpr);
    pairsfin_kernel<<<PAIRT, 256, 0, stream>>>(
        Pt, Gt, term1, px, py, fpr, bgpart, klpart, cntpart, doneCnt, out);
}

// Round 9
// 32.234 us; speedup vs baseline: 4.2254x; 1.1507x over previous
//
#include <hip/hip_runtime.h>
#include <hip/hip_bf16.h>

#define N_N 128
#define N_C 7
#define N_H 96
#define N_W 192
#define HW (N_H * N_W)            // 18432
#define CHW (N_C * HW)            // 129024
#define NHW (N_N * HW)            // 2359296
#define NPTS 100
#define NK (N_N * N_C)            // 896
#define NK2 (NK / 2)              // 448 float2 per row
#define NK4 (NK / 4)              // 224 float4 per row
#define NV (NHW / 4)              // 589824 float4 per tensor (channel 0)
#define HV (HW / 4)               // 4608
#define CV (CHW / 4)              // 32256
#define SIGMA_F 2.0f

#define BG_BLOCKS 1024
#define TILE 4
#define NTILE (NPTS / TILE)       // 25
#define PAIRT (NTILE * (NTILE + 1) / 2)   // 325 tiles with ti<=tj

#define RL __ATOMIC_RELEASE
#define SCOPE __HIP_MEMORY_SCOPE_AGENT

// ---------------- kernel 1 --------------------------------------------------
// blocks 0..1023   : BCE-with-logits partial sums over channel 0
// blocks 1024..1123: gather row i (transposed) + term1[i] + G fingerprint
// block  1124      : zero doneCnt for K2 (replaces hipMemsetAsync node)
__global__ __launch_bounds__(256) void fusedA_kernel(
        const float* __restrict__ in, const float* __restrict__ tg,
        const int* __restrict__ px, const int* __restrict__ py,
        double* __restrict__ bgpart,        // [1024]
        float* __restrict__ Pt,             // [100][896]
        float* __restrict__ Gt,             // [100][896]
        float* __restrict__ term1,          // [100]
        unsigned long long* __restrict__ fpr,  // [100]
        int* __restrict__ doneCnt) {
    __shared__ float swf[4];
    __shared__ unsigned long long swh[4];
    const int b = blockIdx.x;
    const int t = threadIdx.x;
    const int w = t >> 6;
    const int lane = t & 63;

    if (b == BG_BLOCKS + NPTS) {
        if (t == 0) *doneCnt = 0;
        return;
    }

    if (b < BG_BLOCKS) {
        const float4* in4 = (const float4*)in;
        const float4* tg4 = (const float4*)tg;
        float s = 0.0f;
        for (int e = b * 256 + t; e < NV; e += BG_BLOCKS * 256) {
            int n = e / HV;
            int r = e - n * HV;
            float4 x4 = in4[n * CV + r];
            float4 t4 = tg4[n * CV + r];
            const float* xp = &x4.x;
            const float* tp = &t4.x;
#pragma unroll
            for (int q = 0; q < 4; ++q) {
                float x = xp[q], tt = tp[q];
                s += fmaxf(x, 0.0f) - x * tt + log1pf(expf(-fabsf(x)));
            }
        }
#pragma unroll
        for (int m = 32; m >= 1; m >>= 1) s += __shfl_xor(s, m);
        if (lane == 0) swf[w] = s;
        __syncthreads();
        if (t == 0) bgpart[b] = (double)(swf[0] + swf[1] + swf[2] + swf[3]);
    } else {
        const int i = b - BG_BLOCKS;          // 0..99
        const int base = py[i] * N_W + px[i];
        float s = 0.0f;
        unsigned long long h = 0ull;
        for (int k = t; k < NK; k += 256) {
            int n = k / N_C;
            int c = k - n * N_C;
            int off = n * CHW + c * HW + base;
            float p = in[off];
            float g = tg[off];
            Pt[i * NK + k] = p;
            Gt[i * NK + k] = g;
            s += (p > 0.0f) ? p * logf(p) : 0.0f;
            unsigned long long m = (unsigned long long)__float_as_uint(g)
                                 ^ (0x9E3779B97F4A7C15ULL * (unsigned long long)(k + 1));
            m *= 0xC2B2AE3D27D4EB4FULL;
            h ^= m ^ (m >> 31);
        }
#pragma unroll
        for (int m = 32; m >= 1; m >>= 1) {
            s += __shfl_xor(s, m);
            h ^= (unsigned long long)__shfl_xor((long long)h, m);
        }
        if (lane == 0) { swf[w] = s; swh[w] = h; }
        __syncthreads();
        if (t == 0) {
            term1[i] = swf[0] + swf[1] + swf[2] + swf[3];
            fpr[i] = swh[0] ^ swh[1] ^ swh[2] ^ swh[3];
        }
    }
}

// ---------------- kernel 2: upper-triangle LDS-tiled pairs + finalization ---
// 325 blocks: tile (ti,tj), ti<=tj. Wave w owns local i-row w; 4 local j's.
// P-only staging (fingerprints replace G). Last-done block finalizes.
__global__ __launch_bounds__(256) void pairsfin_kernel(
        const float* __restrict__ Pt, const float* __restrict__ Gt,
        const float* __restrict__ term1,
        const int* __restrict__ px, const int* __restrict__ py,
        const unsigned long long* __restrict__ fpr,
        const double* __restrict__ bgpart,   // [1024]
        double* __restrict__ klpart,         // [325]
        int* __restrict__ cntpart,           // [325]
        int* __restrict__ doneCnt,           // [1], zeroed by K1
        float* __restrict__ out) {
    __shared__ __align__(16) float sPI[TILE * NK];   // 14336 B
    __shared__ __align__(16) float sPJ[TILE * NK];   // 14336 B
    __shared__ float sT1[8];
    __shared__ unsigned long long sFp[8];
    __shared__ int sPx[8], sPy[8];
    __shared__ double skl[4];
    __shared__ int scnt4[4];
    __shared__ int slast;
    __shared__ double sred[256];
    __shared__ int sicnt[256];

    const int bidx = blockIdx.x;
    const int t = threadIdx.x;
    const int w = t >> 6;
    const int lane = t & 63;

    // decode bidx -> (ti, tj) with ti <= tj
    int ti = 0, rem = bidx;
    while (rem >= NTILE - ti) { rem -= NTILE - ti; ++ti; }
    const int tj = ti + rem;

    if (t < 8) {
        int g = (t < 4) ? (ti * TILE + t) : (tj * TILE + (t - 4));
        sT1[t] = term1[g];
        sFp[t] = fpr[g];
        sPx[t] = px[g];
        sPy[t] = py[g];
    }
    {   // stage 4 i-rows and 4 j-rows of P (float4 coalesced, 7/thread)
        const float4* Pt4 = (const float4*)Pt;
        float4* sI4 = (float4*)sPI;
        float4* sJ4 = (float4*)sPJ;
        for (int idx = t; idx < TILE * NK4; idx += 256) {
            int r = idx / NK4, q = idx - r * NK4;
            sI4[idx] = Pt4[(ti * TILE + r) * NK4 + q];
            sJ4[idx] = Pt4[(tj * TILE + r) * NK4 + q];
        }
    }
    __syncthreads();

    const float2* sPI2 = (const float2*)sPI;
    const int I = ti * TILE + w;
    float2 piv[7];
#pragma unroll
    for (int it = 0; it < 7; ++it) piv[it] = sPI2[w * NK2 + lane + it * 64];

    double kl = 0.0;
    int cnt = 0;
#pragma unroll
    for (int bb = 0; bb < TILE; ++bb) {
        const int J = tj * TILE + bb;
        const float2* pj2 = (const float2*)(sPJ + bb * NK);
        float cross = 0.0f;
#pragma unroll
        for (int it = 0; it < 7; ++it) {
            float2 pj = pj2[lane + it * 64];
            cross = fmaf(piv[it].x, pj.x, cross);
            cross = fmaf(piv[it].y, pj.y, cross);
        }
#pragma unroll
        for (int m = 32; m >= 1; m >>= 1) cross += __shfl_xor(cross, m);

        bool eqv;
        if (I == J) {
            eqv = true;                          // masked out anyway
        } else if (sFp[w] != sFp[4 + bb]) {
            eqv = false;                         // fp differ -> rows differ (exact)
        } else {
            // rare: fingerprints match, verify exactly from global Gt
            const float2* gi = (const float2*)(Gt + I * NK);
            const float2* gj = (const float2*)(Gt + J * NK);
            int ef = 1;
#pragma unroll
            for (int it = 0; it < 7; ++it) {
                int q = lane + it * 64;
                float2 a = gi[q], c2 = gj[q];
                ef &= (a.x == c2.x) & (a.y == c2.y);
            }
            eqv = __all(ef);
        }
        if (lane == 0) {
            float Dij = (sT1[4 + bb] - cross) * (1.0f / (float)N_N);
            float Dji = (sT1[w] - cross) * (1.0f / (float)N_N);
            float L = eqv ? (Dij + Dji)
                          : (float)(N_N * N_C) *
                            (fmaxf(SIGMA_F - Dij, 0.0f) + fmaxf(SIGMA_F - Dji, 0.0f));
            // count each unordered pair once (I<J); halved sum/cnt keeps the ratio
            bool mask = (I < J) && (sPx[w] != sPx[4 + bb]) && (sPy[w] != sPy[4 + bb]);
            if (mask) { kl += (double)L; cnt += 1; }
        }
    }

    if (lane == 0) { skl[w] = kl; scnt4[w] = cnt; }
    __syncthreads();
    if (t == 0) {
        klpart[bidx] = skl[0] + skl[1] + skl[2] + skl[3];
        cntpart[bidx] = scnt4[0] + scnt4[1] + scnt4[2] + scnt4[3];
        // release: prior stores visible to whoever observes the increment
        int old = __hip_atomic_fetch_add(doneCnt, 1, RL, SCOPE);
        slast = (old == PAIRT - 1) ? 1 : 0;
    }
    __syncthreads();

    if (slast) {
        __builtin_amdgcn_fence(__ATOMIC_ACQUIRE, "agent");   // one invalidate
        double s = 0.0;
        for (int q = t; q < BG_BLOCKS; q += 256) s += bgpart[q];
        double kq = 0.0;
        int cq = 0;
        for (int q = t; q < PAIRT; q += 256) { kq += klpart[q]; cq += cntpart[q]; }
        sred[t] = s;
        __syncthreads();
        for (int off = 128; off > 0; off >>= 1) {
            if (t < off) sred[t] += sred[t + off];
            __syncthreads();
        }
        double bg_sum = sred[0];
        __syncthreads();
        sred[t] = kq;
        sicnt[t] = cq;
        __syncthreads();
        for (int off = 128; off > 0; off >>= 1) {
            if (t < off) { sred[t] += sred[t + off]; sicnt[t] += sicnt[t + off]; }
            __syncthreads();
        }
        if (t == 0)
            out[0] = (float)(bg_sum / (double)NHW + sred[0] / (double)sicnt[0]);
    }
}

// ---------------- launch ---------------------------------------------------
extern "C" void kernel_launch(void* const* d_in, const int* in_sizes, int n_in,
                              void* d_out, int out_size, void* d_ws, size_t ws_size,
                              hipStream_t stream) {
    const float* inputs  = (const float*)d_in[0];
    const float* targets = (const float*)d_in[1];
    const int*   px      = (const int*)d_in[2];
    const int*   py      = (const int*)d_in[3];
    float* out = (float*)d_out;

    char* ws = (char*)d_ws;
    int*    doneCnt = (int*)ws;                           // 128 B reserved
    double* bgpart  = (double*)(ws + 256);                // 1024*8 = 8192
    double* klpart  = (double*)(ws + 8448);               // 325*8 = 2600
    int*    cntpart = (int*)(ws + 11264);                 // 325*4 = 1300
    float*  term1   = (float*)(ws + 12800);               // 100*4
    unsigned long long* fpr = (unsigned long long*)(ws + 13312);  // 100*8
    float*  Pt      = (float*)(ws + 14336);               // 358400
    float*  Gt      = (float*)(ws + 372736);              // 358400

    fusedA_kernel<<<BG_BLOCKS + NPTS + 1, 256, 0, stream>>>(
        inputs, targets, px, py, bgpart, Pt, Gt, term1, fpr, doneCnt);
    pairsfin_kernel<<<PAIRT, 256, 0, stream>>>(
        Pt, Gt, term1, px, py, fpr, bgpart, klpart, cntpart, doneCnt, out);
}